// Round 1
// baseline (28.602 us; speedup 1.0000x reference)
//
#include <hip/hip_runtime.h>

// GriddingReverse: grid (B=32, 64*64*64) f32 -> ptcloud (B, 64^3, 3) f32.
// Output voxel (b, z, y, x): zero if x==0||y==0||z==0 or wsum<=0, else
//   p = ((axis-1) + w_axis1/wsum - D/2) * (2/D)  per axis.
// Flattened j = z*64*64 + y*64 + x, innermost dim = (px,py,pz).

#define DX 64
#define DY 64
#define DZ 64

__global__ __launch_bounds__(256)
void GriddingReverse_kernel(const float* __restrict__ grid,
                            float* __restrict__ out,
                            int total)
{
    int idx = blockIdx.x * blockDim.x + threadIdx.x;
    if (idx >= total) return;

    int x = idx & (DX - 1);
    int y = (idx >> 6) & (DY - 1);
    int z = (idx >> 12) & (DZ - 1);
    int b = idx >> 18;

    float ox = 0.0f, oy = 0.0f, oz = 0.0f;

    if (x > 0 && y > 0 && z > 0) {
        const float* __restrict__ g = grid + ((size_t)b << 18);
        int base = ((z - 1) << 12) + ((y - 1) << 6) + (x - 1);
        float c000 = g[base];
        float c001 = g[base + 1];
        float c010 = g[base + DX];
        float c011 = g[base + DX + 1];
        float c100 = g[base + DX * DY];
        float c101 = g[base + DX * DY + 1];
        float c110 = g[base + DX * DY + DX];
        float c111 = g[base + DX * DY + DX + 1];

        float wsum = ((c000 + c001) + (c010 + c011)) + ((c100 + c101) + (c110 + c111));
        if (wsum > 0.0f) {
            float inv = 1.0f / wsum;
            float wx1 = (c001 + c011) + (c101 + c111);
            float wy1 = (c010 + c011) + (c110 + c111);
            float wz1 = (c100 + c101) + (c110 + c111);
            const float s = 2.0f / 64.0f;   // scaling = 2/D, D=64 all axes
            ox = ((float)(x - 1) + wx1 * inv - 32.0f) * s;
            oy = ((float)(y - 1) + wy1 * inv - 32.0f) * s;
            oz = ((float)(z - 1) + wz1 * inv - 32.0f) * s;
        }
    }

    size_t o = (size_t)idx * 3;
    out[o]     = ox;
    out[o + 1] = oy;
    out[o + 2] = oz;
}

extern "C" void kernel_launch(void* const* d_in, const int* in_sizes, int n_in,
                              void* d_out, int out_size, void* d_ws, size_t ws_size,
                              hipStream_t stream)
{
    const float* grid = (const float*)d_in[0];
    float* out = (float*)d_out;
    int total = in_sizes[0];            // B * 64^3 = 8,388,608 voxels
    int block = 256;
    int ngrid = (total + block - 1) / block;
    GriddingReverse_kernel<<<ngrid, block, 0, stream>>>(grid, out, total);
}